// Round 7
// baseline (45.214 us; speedup 1.0000x reference)
//
#include <hip/hip_runtime.h>
#include <hip/hip_bf16.h>

// Problem: B=N=1024, in_f=1024, OUT_F=32, KD=8
// out[n][0:1024]   = x[n][:]
// M[n][o*8+k]      = sum_f x[n][f] * T[f][o*8+k]        (T flat [1024][256])
// out[n][1024+o]   = sum_{i != n} exp(-sum_k |M[i][o*8+k] - M[n][o*8+k]|)
//
// 3 graph nodes: gemm_split -> reduce_copy -> pairwise6.
// R6 change: pairwise v2 -> v6 (Jpt=2, 256 blocks x 512 thr, all-LDS j-rows).

#define N_ROWS 1024
#define IN_F   1024
#define OUT_C  1056
#define OK     256   // OUT_F*KD
#define KS     8     // K-split factor
#define KC     128   // K-chunk = IN_F/KS

// ---------------- kernel 1: fp32 GEMM with K-split (R1-proven, verbatim) -----
__global__ __launch_bounds__(256) void gemm_split_kernel(
    const float* __restrict__ A,   // x [1024][1024]
    const float* __restrict__ Bm,  // T [1024][256]
    float* __restrict__ part) {    // [KS][1024][256]
  __shared__ float as[64][KC + 4];   // row-major A tile, +4 pad
  __shared__ float bs[KC][64];
  const int m0 = blockIdx.x * 64;
  const int n0 = blockIdx.y * 64;
  const int ks = blockIdx.z;
  const int k0 = ks * KC;
  const int t  = threadIdx.x;

#pragma unroll
  for (int u = 0; u < 8; ++u) {
    int f = t + 256 * u;
    int row = f >> 5, fk = f & 31;           // KC/4 = 32 float4 per row
    float4 v = *reinterpret_cast<const float4*>(A + (size_t)(m0 + row) * IN_F + k0 + fk * 4);
    *reinterpret_cast<float4*>(&as[row][fk * 4]) = v;
  }
#pragma unroll
  for (int u = 0; u < 8; ++u) {
    int f = t + 256 * u;
    int row = f >> 4, fc = f & 15;
    float4 v = *reinterpret_cast<const float4*>(Bm + (size_t)(k0 + row) * OK + n0 + fc * 4);
    *reinterpret_cast<float4*>(&bs[row][fc * 4]) = v;
  }
  __syncthreads();

  const int ty = t >> 4, tx = t & 15;   // 16x16 thread grid, 4x4 outputs each
  float acc[4][4] = {};

  for (int kk = 0; kk < KC; kk += 4) {
    float av[4][4], bv[4][4];
#pragma unroll
    for (int r = 0; r < 4; ++r)
      *reinterpret_cast<float4*>(av[r]) = *reinterpret_cast<const float4*>(&as[ty * 4 + r][kk]);
#pragma unroll
    for (int i = 0; i < 4; ++i)
      *reinterpret_cast<float4*>(bv[i]) = *reinterpret_cast<const float4*>(&bs[kk + i][tx * 4]);
#pragma unroll
    for (int i = 0; i < 4; ++i)
#pragma unroll
      for (int r = 0; r < 4; ++r)
#pragma unroll
        for (int c = 0; c < 4; ++c)
          acc[r][c] = fmaf(av[r][i], bv[i][c], acc[r][c]);
  }

  float* dst = part + (size_t)ks * N_ROWS * OK;
#pragma unroll
  for (int r = 0; r < 4; ++r)
    *reinterpret_cast<float4*>(&dst[(size_t)(m0 + ty * 4 + r) * OK + n0 + tx * 4]) =
        *reinterpret_cast<const float4*>(acc[r]);
}

// ---------------- kernel 2: reduce K-split partials + copy x into out --------
__global__ __launch_bounds__(256) void reduce_copy_kernel(
    const float* __restrict__ part, float* __restrict__ M,
    const float* __restrict__ x, float* __restrict__ out) {
  const int b = blockIdx.x, t = threadIdx.x;

  if (t < 128) {
    int g = b * 128 + t;
    const float4* p = reinterpret_cast<const float4*>(part);
    float4 s = p[g];
#pragma unroll
    for (int sl = 1; sl < KS; ++sl) {
      float4 v = p[g + (size_t)sl * (N_ROWS * OK / 4)];
      s.x += v.x; s.y += v.y; s.z += v.z; s.w += v.w;
    }
    reinterpret_cast<float4*>(M)[g] = s;
  }

#pragma unroll
  for (int u = 0; u < 2; ++u) {
    int idx = b * 512 + u * 256 + t;
    int row = idx >> 8, col4 = idx & 255;     // 256 float4 per row
    float4 v = *reinterpret_cast<const float4*>(x + (size_t)row * IN_F + col4 * 4);
    *reinterpret_cast<float4*>(out + (size_t)row * OUT_C + col4 * 4) = v;
  }
}

// ---------------- fallback GEMM (small ws): single-pass ----------------
#define BK 16
__global__ __launch_bounds__(256) void gemm32_kernel(
    const float* __restrict__ A, const float* __restrict__ Bm, float* __restrict__ M) {
  __shared__ float as2[BK][32];
  __shared__ float bs2[BK][32];
  int m0 = blockIdx.x * 32;
  int n0 = blockIdx.y * 32;
  int t  = threadIdx.x;
  int ty = t >> 4, tx = t & 15;
  float c00 = 0.f, c01 = 0.f, c10 = 0.f, c11 = 0.f;
  for (int k0 = 0; k0 < IN_F; k0 += BK) {
    if (t < 128) {
      int row = t >> 2, q = t & 3;
      float4 v = *reinterpret_cast<const float4*>(A + (size_t)(m0 + row) * IN_F + k0 + q * 4);
      as2[q * 4 + 0][row] = v.x; as2[q * 4 + 1][row] = v.y;
      as2[q * 4 + 2][row] = v.z; as2[q * 4 + 3][row] = v.w;
    } else {
      int tt = t - 128;
      int row = tt >> 3, q = tt & 7;
      float4 v = *reinterpret_cast<const float4*>(Bm + (size_t)(k0 + row) * OK + n0 + q * 4);
      *reinterpret_cast<float4*>(&bs2[row][q * 4]) = v;
    }
    __syncthreads();
#pragma unroll
    for (int kk = 0; kk < BK; ++kk) {
      float2 a = *reinterpret_cast<const float2*>(&as2[kk][ty * 2]);
      float2 b = *reinterpret_cast<const float2*>(&bs2[kk][tx * 2]);
      c00 += a.x * b.x; c01 += a.x * b.y;
      c10 += a.y * b.x; c11 += a.y * b.y;
    }
    __syncthreads();
  }
  int r = m0 + ty * 2, c = n0 + tx * 2;
  M[(size_t)r * OK + c]           = c00;
  M[(size_t)r * OK + c + 1]       = c01;
  M[(size_t)(r + 1) * OK + c]     = c10;
  M[(size_t)(r + 1) * OK + c + 1] = c11;
}

// ---------------- kernel 3: pairwise exp(-L1) v6 -----------------------------
// grid (o:32, jt:8) = 256 blocks, 512 threads (8 waves). Stage ALL 1024 i-rows
// (32 KB). Thread owns j0 = jt*128 + (t&63) and j1 = j0+64 (read from LDS,
// named float4 regs). Wave s covers i in [s*128, s*128+128) -> 2 broadcast
// ds_read_b128 serve 2 j's (halves LDS issue vs v2). Wave partials -> LDS
// reduce -> direct store (no atomics).
__global__ __launch_bounds__(512) void pairwise6_kernel(
    const float* __restrict__ M, float* __restrict__ out) {
  __shared__ float sm[N_ROWS][8];   // 32 KB: M[:, o, :]
  __shared__ float red[8][128];     // 4 KB wave partials

  const int o  = blockIdx.x;   // 0..31
  const int jt = blockIdx.y;   // 0..7
  const int t  = threadIdx.x;
  const int jl = t & 63, s = t >> 6;

  // stage all 1024 i-rows: 2048 float4 over 512 threads, coalesced
  for (int idx = t; idx < 2048; idx += 512) {
    int row = idx >> 1, half = idx & 1;
    *reinterpret_cast<float4*>(&sm[row][half * 4]) =
        *reinterpret_cast<const float4*>(M + (size_t)row * OK + o * 8 + half * 4);
  }
  __syncthreads();

  const int j0 = jt * 128 + jl, j1 = j0 + 64;
  float4 ra0 = *reinterpret_cast<const float4*>(&sm[j0][0]);
  float4 rb0 = *reinterpret_cast<const float4*>(&sm[j0][4]);
  float4 ra1 = *reinterpret_cast<const float4*>(&sm[j1][0]);
  float4 rb1 = *reinterpret_cast<const float4*>(&sm[j1][4]);

  float acc0 = 0.f, acc1 = 0.f;
  const int ib = s * 128;
  for (int ii = 0; ii < 128; ++ii) {
    float4 va = *reinterpret_cast<const float4*>(&sm[ib + ii][0]);
    float4 vb = *reinterpret_cast<const float4*>(&sm[ib + ii][4]);
    float d0 = (fabsf(va.x - ra0.x) + fabsf(va.y - ra0.y)) +
               (fabsf(va.z - ra0.z) + fabsf(va.w - ra0.w)) +
               (fabsf(vb.x - rb0.x) + fabsf(vb.y - rb0.y)) +
               (fabsf(vb.z - rb0.z) + fabsf(vb.w - rb0.w));
    float d1 = (fabsf(va.x - ra1.x) + fabsf(va.y - ra1.y)) +
               (fabsf(va.z - ra1.z) + fabsf(va.w - ra1.w)) +
               (fabsf(vb.x - rb1.x) + fabsf(vb.y - rb1.y)) +
               (fabsf(vb.z - rb1.z) + fabsf(vb.w - rb1.w));
    // exp(-d) < e^-30 contributes < 1e-10 total over 1024 terms -> skip.
    if (fminf(d0, d1) < 30.f) {
      acc0 += __expf(-d0);
      acc1 += __expf(-d1);
    }
  }
  // exact self term (exp(0)=1): i==j0 falls in wave j0>>7, same for j1
  if ((j0 >> 7) == s) acc0 -= 1.f;
  if ((j1 >> 7) == s) acc1 -= 1.f;

  red[s][jl]      = acc0;
  red[s][jl + 64] = acc1;
  __syncthreads();

  if (t < 128) {
    float v = 0.f;
#pragma unroll
    for (int w = 0; w < 8; ++w) v += red[w][t];
    out[(size_t)(jt * 128 + t) * OUT_C + 1024 + o] = v;
  }
}

extern "C" void kernel_launch(void* const* d_in, const int* in_sizes, int n_in,
                              void* d_out, int out_size, void* d_ws, size_t ws_size,
                              hipStream_t stream) {
  const float* x = (const float*)d_in[0];   // [1024][1024]
  const float* T = (const float*)d_in[1];   // [1024][256]
  float* out = (float*)d_out;               // [1024][1056]

  const size_t mBytes    = (size_t)N_ROWS * OK * sizeof(float);   // 1 MB
  const size_t partBytes = (size_t)KS * mBytes;                   // 8 MB

  if (ws_size >= partBytes + mBytes) {
    float* part = (float*)d_ws;
    float* M    = (float*)((char*)d_ws + partBytes);
    gemm_split_kernel<<<dim3(16, 4, KS), dim3(256), 0, stream>>>(x, T, part);
    reduce_copy_kernel<<<dim3(512), dim3(256), 0, stream>>>(part, M, x, out);
    pairwise6_kernel<<<dim3(32, 8), dim3(512), 0, stream>>>(M, out);
  } else {
    float* M = (float*)d_ws;
    // fallback path: copy fused into reduce impossible (no part); reuse gemm32
    gemm32_kernel<<<dim3(32, 8), dim3(256), 0, stream>>>(x, T, M);
    // copy x via reduce_copy's copy loop semantics (simple per-row kernel)
    // small standalone copy:
    // (declared below to keep node count low on main path only)
    struct Local {};
    // inline copy kernel launch
    extern __global__ void copy_x_kernel(const float*, float*);
    copy_x_kernel<<<dim3(N_ROWS), dim3(256), 0, stream>>>(x, out);
    pairwise6_kernel<<<dim3(32, 8), dim3(512), 0, stream>>>(M, out);
  }
}

// fallback copy (only used on fallback path)
__global__ __launch_bounds__(256) void copy_x_kernel(
    const float* __restrict__ x, float* __restrict__ out) {
  int n = blockIdx.x;
  int c = threadIdx.x * 4;
  float4 v = *reinterpret_cast<const float4*>(x + (size_t)n * IN_F + c);
  *reinterpret_cast<float4*>(out + (size_t)n * OUT_C + c) = v;
}

// Round 8
// 43.008 us; speedup vs baseline: 1.0513x; 1.0513x over previous
//
#include <hip/hip_runtime.h>
#include <hip/hip_bf16.h>

// Problem: B=N=1024, in_f=1024, OUT_F=32, KD=8
// out[n][0:1024]   = x[n][:]
// M[n][o*8+k]      = sum_f x[n][f] * T[f][o*8+k]        (T flat [1024][256])
// out[n][1024+o]   = sum_{i != n} exp(-sum_k |M[i][o*8+k] - M[n][o*8+k]|)
//
// R7: GEMM moves to bf16 MFMA (error budget: o_b terms <= 1e-10, threshold 0.099).
// 4 nodes: prep -> gemm_mfma -> reduce -> pairwise(v2 verbatim, proven best).

#define N_ROWS 1024
#define IN_F   1024
#define OUT_C  1056
#define OK     256   // OUT_F*KD
#define KS     8     // K-split factor
#define KC     128   // K-chunk = IN_F/KS

typedef __attribute__((ext_vector_type(8))) short bf16x8;
typedef __attribute__((ext_vector_type(4))) float f32x4;

__device__ __forceinline__ unsigned short f2bf(float f) {
  unsigned u = __float_as_uint(f);
  u = (u + 0x7FFFu + ((u >> 16) & 1u)) >> 16;   // RNE
  return (unsigned short)u;
}

// ---------------- kernel 1: prep ---------------------------------------------
// blocks 0-511: copy x -> out[:,0:1024] and convert x -> xb (bf16)
// blocks 512-575: transpose T [1024][256] fp32 -> Tt [256][1024] bf16
__global__ __launch_bounds__(256) void prep_kernel(
    const float* __restrict__ x, const float* __restrict__ T,
    float* __restrict__ out, unsigned short* __restrict__ xb,
    unsigned short* __restrict__ Tt) {
  const int b = blockIdx.x, t = threadIdx.x;
  if (b < 512) {
#pragma unroll
    for (int u = 0; u < 2; ++u) {
      int idx = b * 512 + u * 256 + t;          // 262144 float4 groups
      int row = idx >> 8, col4 = idx & 255;     // 256 float4 per row
      float4 v = *reinterpret_cast<const float4*>(x + (size_t)row * IN_F + col4 * 4);
      *reinterpret_cast<float4*>(out + (size_t)row * OUT_C + col4 * 4) = v;
      ushort4 h = make_ushort4(f2bf(v.x), f2bf(v.y), f2bf(v.z), f2bf(v.w));
      *reinterpret_cast<ushort4*>(xb + (size_t)row * IN_F + col4 * 4) = h;
    }
  } else {
    // 64 blocks x 4 cols: thread handles col c, k-range [g*16, g*16+16)
    int c = (b - 512) * 4 + (t >> 6);   // 0..255
    int g = t & 63;
#pragma unroll
    for (int u = 0; u < 2; ++u) {
      int k0 = g * 16 + u * 8;
      unsigned short h[8];
#pragma unroll
      for (int j = 0; j < 8; ++j)
        h[j] = f2bf(T[(size_t)(k0 + j) * OK + c]);   // scattered reads (L2, T=1MB)
      *reinterpret_cast<uint4*>(Tt + (size_t)c * IN_F + k0) =
          *reinterpret_cast<const uint4*>(h);         // coalesced 16B store
    }
  }
}

// ---------------- kernel 2: bf16 MFMA GEMM, 64x64 tile, K-split 8 ------------
// Same schedule as the proven gemm_split: one-shot stage, ONE barrier, compute.
// LDS tiles swizzled on 16B slots: slot' = slot ^ (row & 15) (2-way max = free).
// Wave w: rows [w*16,+16), 4 n-tiles x 4 k-steps = 16 MFMA (16x16x32 bf16).
__global__ __launch_bounds__(256) void gemm_mfma_kernel(
    const unsigned short* __restrict__ xb,  // [1024][1024] bf16
    const unsigned short* __restrict__ Tt,  // [256][1024] bf16 (T transposed)
    float* __restrict__ part) {             // [KS][1024][256]
  __shared__ unsigned short asw[64 * 128];  // 16 KB A tile  (row-major, swizzled)
  __shared__ unsigned short bsw[64 * 128];  // 16 KB B tile  (col-major via Tt)
  const int m0 = blockIdx.x * 64;
  const int n0 = blockIdx.y * 64;
  const int ks = blockIdx.z;
  const int t  = threadIdx.x;

  // stage A and B: 1024 x 16B each, 4 rounds, coalesced; swizzled LDS writes
#pragma unroll
  for (int u = 0; u < 4; ++u) {
    int idx = t + 256 * u;
    int row = idx >> 4, slot = idx & 15;        // 16 x 16B slots per 128-bf16 row
    uint4 va = *reinterpret_cast<const uint4*>(
        xb + (size_t)(m0 + row) * IN_F + ks * KC + slot * 8);
    *reinterpret_cast<uint4*>(asw + row * 128 + ((slot ^ (row & 15)) * 8)) = va;
    uint4 vb = *reinterpret_cast<const uint4*>(
        Tt + (size_t)(n0 + row) * IN_F + ks * KC + slot * 8);
    *reinterpret_cast<uint4*>(bsw + row * 128 + ((slot ^ (row & 15)) * 8)) = vb;
  }
  __syncthreads();

  const int l  = t & 63, w = t >> 6;
  const int lr = l & 15, lg = l >> 4;   // lane-row/col, lane k-group
  f32x4 acc0 = {0.f, 0.f, 0.f, 0.f};
  f32x4 acc1 = {0.f, 0.f, 0.f, 0.f};
  f32x4 acc2 = {0.f, 0.f, 0.f, 0.f};
  f32x4 acc3 = {0.f, 0.f, 0.f, 0.f};

  const int arow = w * 16 + lr;
  const int aswz = arow & 15;
#pragma unroll
  for (int kk = 0; kk < 4; ++kk) {
    int slotA = kk * 4 + lg;             // A,B frag: k = kk*32 + lg*8 + j
    bf16x8 a = *reinterpret_cast<const bf16x8*>(
        asw + arow * 128 + ((slotA ^ aswz) * 8));
    int sb = (slotA ^ lr) * 8;           // B col & 15 == lr for every n-tile
    bf16x8 b0 = *reinterpret_cast<const bf16x8*>(bsw + (lr)      * 128 + sb);
    bf16x8 b1 = *reinterpret_cast<const bf16x8*>(bsw + (16 + lr) * 128 + sb);
    bf16x8 b2 = *reinterpret_cast<const bf16x8*>(bsw + (32 + lr) * 128 + sb);
    bf16x8 b3 = *reinterpret_cast<const bf16x8*>(bsw + (48 + lr) * 128 + sb);
    acc0 = __builtin_amdgcn_mfma_f32_16x16x32_bf16(a, b0, acc0, 0, 0, 0);
    acc1 = __builtin_amdgcn_mfma_f32_16x16x32_bf16(a, b1, acc1, 0, 0, 0);
    acc2 = __builtin_amdgcn_mfma_f32_16x16x32_bf16(a, b2, acc2, 0, 0, 0);
    acc3 = __builtin_amdgcn_mfma_f32_16x16x32_bf16(a, b3, acc3, 0, 0, 0);
  }

  // C/D layout (m89-verified): col = lane&15, row = (lane>>4)*4 + reg
  float* dst = part + (size_t)ks * (N_ROWS * OK)
             + (size_t)(m0 + w * 16 + lg * 4) * OK + n0 + lr;
#pragma unroll
  for (int r = 0; r < 4; ++r) {
    dst[(size_t)r * OK]      = acc0[r];
    dst[(size_t)r * OK + 16] = acc1[r];
    dst[(size_t)r * OK + 32] = acc2[r];
    dst[(size_t)r * OK + 48] = acc3[r];
  }
}

// ---------------- kernel 3: reduce K-split partials --------------------------
__global__ __launch_bounds__(256) void reduce_kernel(
    const float* __restrict__ part, float* __restrict__ M) {
  int g = blockIdx.x * 256 + threadIdx.x;         // 65536 float4 groups
  const float4* p = reinterpret_cast<const float4*>(part);
  float4 s = p[g];
#pragma unroll
  for (int sl = 1; sl < KS; ++sl) {
    float4 v = p[g + (size_t)sl * (N_ROWS * OK / 4)];
    s.x += v.x; s.y += v.y; s.z += v.z; s.w += v.w;
  }
  reinterpret_cast<float4*>(M)[g] = s;
}

// ---------------- fallback GEMM (small ws): single-pass fp32 -----------------
#define BK 16
__global__ __launch_bounds__(256) void gemm32_kernel(
    const float* __restrict__ A, const float* __restrict__ Bm, float* __restrict__ M) {
  __shared__ float as2[BK][32];
  __shared__ float bs2[BK][32];
  int m0 = blockIdx.x * 32;
  int n0 = blockIdx.y * 32;
  int t  = threadIdx.x;
  int ty = t >> 4, tx = t & 15;
  float c00 = 0.f, c01 = 0.f, c10 = 0.f, c11 = 0.f;
  for (int k0 = 0; k0 < IN_F; k0 += BK) {
    if (t < 128) {
      int row = t >> 2, q = t & 3;
      float4 v = *reinterpret_cast<const float4*>(A + (size_t)(m0 + row) * IN_F + k0 + q * 4);
      as2[q * 4 + 0][row] = v.x; as2[q * 4 + 1][row] = v.y;
      as2[q * 4 + 2][row] = v.z; as2[q * 4 + 3][row] = v.w;
    } else {
      int tt = t - 128;
      int row = tt >> 3, q = tt & 7;
      float4 v = *reinterpret_cast<const float4*>(Bm + (size_t)(k0 + row) * OK + n0 + q * 4);
      *reinterpret_cast<float4*>(&bs2[row][q * 4]) = v;
    }
    __syncthreads();
#pragma unroll
    for (int kk = 0; kk < BK; ++kk) {
      float2 a = *reinterpret_cast<const float2*>(&as2[kk][ty * 2]);
      float2 b = *reinterpret_cast<const float2*>(&bs2[kk][tx * 2]);
      c00 += a.x * b.x; c01 += a.x * b.y;
      c10 += a.y * b.x; c11 += a.y * b.y;
    }
    __syncthreads();
  }
  int r = m0 + ty * 2, c = n0 + tx * 2;
  M[(size_t)r * OK + c]           = c00;
  M[(size_t)r * OK + c + 1]       = c01;
  M[(size_t)(r + 1) * OK + c]     = c10;
  M[(size_t)(r + 1) * OK + c + 1] = c11;
}

// ---------------- kernel 4: pairwise exp(-L1) (R1/R5-proven, verbatim) -------
// grid = (o: 32, jt: 16) = 512 blocks, 256 threads, stages all 1024 i-rows.
__global__ __launch_bounds__(256) void pairwise_kernel(
    const float* __restrict__ M, float* __restrict__ out) {
  __shared__ float sm[N_ROWS][8];   // 32 KB: M[:, o, :]
  __shared__ float red[4][64];

  int o  = blockIdx.x;
  int jt = blockIdx.y;
  int t  = threadIdx.x;

#pragma unroll
  for (int idx = t; idx < 2048; idx += 256) {
    int row = idx >> 1, half = idx & 1;
    *reinterpret_cast<float4*>(&sm[row][half * 4]) =
        *reinterpret_cast<const float4*>(M + (size_t)row * OK + o * 8 + half * 4);
  }
  __syncthreads();

  int jl = t & 63, s = t >> 6;
  int j  = jt * 64 + jl;

  float4 ra = *reinterpret_cast<const float4*>(&sm[j][0]);
  float4 rb = *reinterpret_cast<const float4*>(&sm[j][4]);

  float acc = 0.f;
  int i0 = s * 256;
  for (int i = i0; i < i0 + 256; ++i) {
    float4 va = *reinterpret_cast<const float4*>(&sm[i][0]);
    float4 vb = *reinterpret_cast<const float4*>(&sm[i][4]);
    float d = fabsf(va.x - ra.x) + fabsf(va.y - ra.y) +
              fabsf(va.z - ra.z) + fabsf(va.w - ra.w) +
              fabsf(vb.x - rb.x) + fabsf(vb.y - rb.y) +
              fabsf(vb.z - rb.z) + fabsf(vb.w - rb.w);
    // exp(-d) < e^-30: contributes < 1e-10 total over 1024 terms -> skip
    if (d < 30.f) acc += __expf(-d);
  }
  if ((j >> 8) == s) acc -= 1.0f;   // exact self term exp(0)=1

  red[s][jl] = acc;
  __syncthreads();

  if (t < 64) {
    float v = red[0][t] + red[1][t] + red[2][t] + red[3][t];
    int jj = jt * 64 + t;
    out[(size_t)jj * OUT_C + 1024 + o] = v;
  }
}

// fallback copy (only used on fallback path)
__global__ __launch_bounds__(256) void copy_x_kernel(
    const float* __restrict__ x, float* __restrict__ out) {
  int n = blockIdx.x;
  int c = threadIdx.x * 4;
  float4 v = *reinterpret_cast<const float4*>(x + (size_t)n * IN_F + c);
  *reinterpret_cast<float4*>(out + (size_t)n * OUT_C + c) = v;
}

extern "C" void kernel_launch(void* const* d_in, const int* in_sizes, int n_in,
                              void* d_out, int out_size, void* d_ws, size_t ws_size,
                              hipStream_t stream) {
  const float* x = (const float*)d_in[0];   // [1024][1024]
  const float* T = (const float*)d_in[1];   // [1024][256]
  float* out = (float*)d_out;               // [1024][1056]

  const size_t mElems = (size_t)N_ROWS * OK;           // 262144
  const size_t needed = KS * mElems * 4                // part  8 MB
                      + mElems * 4                     // M     1 MB
                      + (size_t)N_ROWS * IN_F * 2      // xb    2 MB
                      + (size_t)OK * IN_F * 2;         // Tt  0.5 MB

  if (ws_size >= needed) {
    float* part = (float*)d_ws;
    float* M    = part + KS * mElems;
    unsigned short* xb = (unsigned short*)(M + mElems);
    unsigned short* Tt = xb + (size_t)N_ROWS * IN_F;

    prep_kernel<<<dim3(576), dim3(256), 0, stream>>>(x, T, out, xb, Tt);
    gemm_mfma_kernel<<<dim3(16, 4, KS), dim3(256), 0, stream>>>(xb, Tt, part);
    reduce_kernel<<<dim3(256), dim3(256), 0, stream>>>(part, M);
    pairwise_kernel<<<dim3(32, 16), dim3(256), 0, stream>>>(M, out);
  } else {
    float* M = (float*)d_ws;
    copy_x_kernel<<<dim3(N_ROWS), dim3(256), 0, stream>>>(x, out);
    gemm32_kernel<<<dim3(32, 8), dim3(256), 0, stream>>>(x, T, M);
    pairwise_kernel<<<dim3(32, 16), dim3(256), 0, stream>>>(M, out);
  }
}